// Round 9
// baseline (236.441 us; speedup 1.0000x reference)
//
#include <hip/hip_runtime.h>
#include <cstdint>
#include <cstddef>

#define L_SEQ 2048
#define BATCH 8
#define DIN   1024
#define PDIM  512
#define DOUT  1024
#define MROWS (L_SEQ * BATCH)   // 16384

typedef __attribute__((ext_vector_type(4))) float f32x4;
typedef __attribute__((ext_vector_type(8))) short bf16x8;

__device__ __forceinline__ unsigned short f2bf(float f) {
  union { float f; unsigned int u; } v; v.f = f;
  unsigned int u = v.u;
  unsigned int r = (u + 0x7FFFu + ((u >> 16) & 1u)) >> 16;
  return (unsigned short)r;
}
__device__ __forceinline__ float bf2f(unsigned short h) {
  union { unsigned int u; float f; } v; v.u = ((unsigned int)h) << 16;
  return v.f;
}

// async global->LDS, 16 bytes per lane; dest is wave-uniform base + lane*16
__device__ __forceinline__ void gld16(const unsigned short* g, unsigned short* l) {
  __builtin_amdgcn_global_load_lds(
      (const __attribute__((address_space(1))) void*)g,
      (__attribute__((address_space(3))) void*)l,
      16, 0, 0);
}

// T1: bijective XCD-chunked block remap (m204).
__device__ __forceinline__ int swz_lin(int lin, int nwg) {
  int q = nwg >> 3, r = nwg & 7;
  int xcd = lin & 7;
  int base = (xcd < r) ? xcd * (q + 1) : r * (q + 1) + (xcd - r) * q;
  return base + (lin >> 3);
}

// ---------------- fp32 -> bf16 convert (vectorized) ----------------
__global__ void convert_f32_bf16(const float* __restrict__ in,
                                 unsigned short* __restrict__ out, int n4) {
  int i = blockIdx.x * blockDim.x + threadIdx.x;
  int stride = gridDim.x * blockDim.x;
  for (; i < n4; i += stride) {
    float4 v = reinterpret_cast<const float4*>(in)[i];
    ushort4 o;
    o.x = f2bf(v.x); o.y = f2bf(v.y); o.z = f2bf(v.z); o.w = f2bf(v.w);
    reinterpret_cast<ushort4*>(out)[i] = o;
  }
}

// ---------------- V transpose: kv[l][b][512+p] -> vt[b][p][l] ----------------
__global__ void transpose_v_kernel(const unsigned short* __restrict__ kv,
                                   unsigned short* __restrict__ vt) {
  __shared__ unsigned short tile[32][33];
  int b = blockIdx.z;
  int l0 = blockIdx.x * 32;
  int p0 = blockIdx.y * 32;
  const unsigned short* src = kv + (size_t)b * (2 * PDIM) + PDIM;
  unsigned short* dst = vt + (size_t)b * PDIM * L_SEQ;
  int tx = threadIdx.x, ty = threadIdx.y;
  #pragma unroll
  for (int r = ty; r < 32; r += 8)
    tile[r][tx] = src[(size_t)(l0 + r) * (BATCH * 2 * PDIM) + p0 + tx];
  __syncthreads();
  #pragma unroll
  for (int r = ty; r < 32; r += 8)
    dst[(size_t)(p0 + r) * L_SEQ + l0 + tx] = tile[tx][r];
}

// ---------------- row softmax with causal mask (bf16 in / in-place bf16 out) -
__global__ void softmax_causal(unsigned short* __restrict__ S,
                               size_t strideB, float scale) {
  __shared__ float buf[L_SEQ];
  __shared__ float red[4];
  int b = blockIdx.z;
  int i = blockIdx.x;                       // causal row index
  unsigned short* row = S + b * strideB + (size_t)i * L_SEQ;
  int t = threadIdx.x;
  int lane = t & 63, wid = t >> 6;

  float lmax = -3.0e38f;
  for (int j = t; j <= i; j += 256) {
    float v = bf2f(row[j]) * scale;
    buf[j] = v;
    lmax = fmaxf(lmax, v);
  }
  #pragma unroll
  for (int o = 32; o > 0; o >>= 1) lmax = fmaxf(lmax, __shfl_xor(lmax, o));
  if (lane == 0) red[wid] = lmax;
  __syncthreads();
  float m = fmaxf(fmaxf(red[0], red[1]), fmaxf(red[2], red[3]));

  float lsum = 0.0f;
  for (int j = t; j <= i; j += 256) {
    float e = __expf(buf[j] - m);
    buf[j] = e;
    lsum += e;
  }
  #pragma unroll
  for (int o = 32; o > 0; o >>= 1) lsum += __shfl_xor(lsum, o);
  __syncthreads();
  if (lane == 0) red[wid] = lsum;
  __syncthreads();
  float inv = 1.0f / (red[0] + red[1] + red[2] + red[3]);

  int jmax = ((i >> 7) + 1) << 7;
  for (int j = t; j < jmax; j += 256)
    row[j] = (j <= i) ? f2bf(buf[j] * inv) : (unsigned short)0;
}

// ---------------- bf16 MFMA GEMM 128²: 2-phase dbuf (R6-verified) ----------
#define BM 128
#define BK 64

template<int EPI, int TBN>
__global__ __launch_bounds__(256)
void gemm_bt(const unsigned short* __restrict__ A,
             const unsigned short* __restrict__ B,
             void* __restrict__ C,
             const unsigned short* __restrict__ R,
             int M, int N, int K, int lda, int ldb, int ldc,
             size_t sAb, size_t sBb, size_t sCb, size_t sRb,
             int mode) {
  constexpr int MF   = (TBN == 128) ? 4 : 2;
  constexpr int BITS = TBN / 32;

  int gx = gridDim.x, gy = gridDim.y;
  int nwg = gx * gy * (int)gridDim.z;
  int lin = ((int)blockIdx.z * gy + (int)blockIdx.y) * gx + (int)blockIdx.x;
  int wg = swz_lin(lin, nwg);
  int bx = wg % gx;
  int rem = wg / gx;
  int by = rem % gy;
  int bz = rem / gy;

  A += (size_t)bz * sAb;
  B += (size_t)bz * sBb;
  R += (size_t)bz * sRb;
  float* Cf = (float*)C + (size_t)bz * sCb;
  unsigned short* Ch = (unsigned short*)C + (size_t)bz * sCb;

  __shared__ unsigned short As[2][BM * BK];
  __shared__ unsigned short Bs[2][TBN * BK];

  int t = threadIdx.x;
  int lane = t & 63;
  int wid = t >> 6;
  int wr = (TBN == 128) ? (wid >> 1) * 64 : wid * 32;
  int wc = (TBN == 128) ? (wid & 1) * 64 : 0;
  int lr = lane & 15;
  int kof = (lane >> 4) * 8;
  int srow = lane >> 3;
  int scol = (lane & 7) * 8;

  int npass = (mode == 2) ? 2 : 1;

  for (int pass = 0; pass < npass; ++pass) {
    int tmTile, tnBase;
    if (mode == 1) {
      int t3 = bx;
      int tm3 = 0;
      while ((tm3 + 1) * (tm3 + 2) / 2 <= t3) tm3++;
      tmTile = tm3;
      tnBase = (t3 - tm3 * (tm3 + 1) / 2) * TBN;
    } else if (mode == 2) {
      int nt = M / BM;
      tmTile = pass ? (nt - 1 - by) : by;
      tnBase = bx * TBN;
    } else {
      tmTile = by;
      tnBase = bx * TBN;
    }
    int tm = tmTile * BM;
    int kEnd = (mode == 2) ? ((tm + BM) < K ? (tm + BM) : K) : K;
    int nk = kEnd / BK;

    f32x4 acc[MF][4];
    f32x4 zero = {0.0f, 0.0f, 0.0f, 0.0f};
    #pragma unroll
    for (int m = 0; m < MF; ++m)
      #pragma unroll
      for (int n = 0; n < 4; ++n) acc[m][n] = zero;

    auto stage = [&](int bi, int ks) {
      int k0 = ks * BK;
      #pragma unroll
      for (int it = 0; it < 4; ++it) {
        int r = wid * 32 + it * 8;
        gld16(A + (size_t)(tm + r + srow) * lda + k0 + scol, &As[bi][r * BK]);
      }
      #pragma unroll
      for (int it = 0; it < BITS; ++it) {
        int r = wid * (TBN / 4) + it * 8;
        gld16(B + (size_t)(tnBase + r + srow) * ldb + k0 + scol, &Bs[bi][r * BK]);
      }
    };

    stage(0, 0);
    for (int ks = 0; ks < nk; ++ks) {
      int bi = ks & 1;
      if (ks + 1 < nk) {
        stage(bi ^ 1, ks + 1);
        if constexpr (TBN == 128)
          asm volatile("s_waitcnt vmcnt(8)" ::: "memory");
        else
          asm volatile("s_waitcnt vmcnt(6)" ::: "memory");
      } else {
        asm volatile("s_waitcnt vmcnt(0)" ::: "memory");
      }
      __builtin_amdgcn_s_barrier();
      __builtin_amdgcn_sched_barrier(0);

      #pragma unroll
      for (int kk = 0; kk < BK; kk += 32) {
        bf16x8 af[MF], bfr[4];
        #pragma unroll
        for (int m = 0; m < MF; ++m)
          af[m] = *(const bf16x8*)&As[bi][(wr + m * 16 + lr) * BK + kk + kof];
        #pragma unroll
        for (int n = 0; n < 4; ++n)
          bfr[n] = *(const bf16x8*)&Bs[bi][(wc + n * 16 + lr) * BK + kk + kof];
        #pragma unroll
        for (int m = 0; m < MF; ++m)
          #pragma unroll
          for (int n = 0; n < 4; ++n)
            acc[m][n] = __builtin_amdgcn_mfma_f32_16x16x32_bf16(af[m], bfr[n], acc[m][n], 0, 0, 0);
      }
      asm volatile("" ::: "memory");
      __builtin_amdgcn_s_barrier();
      __builtin_amdgcn_sched_barrier(0);
    }

    int rb0 = tm + wr + (lane >> 4) * 4;
    #pragma unroll
    for (int m = 0; m < MF; ++m) {
      #pragma unroll
      for (int n = 0; n < 4; ++n) {
        int col = tnBase + wc + n * 16 + lr;
        #pragma unroll
        for (int j = 0; j < 4; ++j) {
          int row = rb0 + m * 16 + j;
          float v = acc[m][n][j];
          size_t idx = (size_t)row * ldc + col;
          if constexpr (EPI == 1) {
            Cf[idx] = v;
          } else if constexpr (EPI == 2) {
            Ch[idx] = f2bf(v + bf2f(R[idx]));
          } else {
            Ch[idx] = f2bf(v);
          }
        }
      }
    }
  }
}

// ---------------- bf16 MFMA GEMM 256²: 8-phase schedule (T3+T4+T5) ---------
// 8 waves (2M x 4N), BK=64, 128KB LDS (2 dbuf x (A 32KB + B 32KB)).
// Quadrant order per K-tile: (mh0,nh0)(mh0,nh1)(mh1,nh1)(mh1,nh0), B0 kept
// in regs ph1->ph4 so LDS B frees after ph2, A after ph3. Stage slots
// ph1..8 = A(b)h0, A(b)h1, B(a+2)h0, B(a+2)h1, A(a+2)h0, A(a+2)h1,
// B(b+2)h0, B(b+2)h1. vmcnt(4) at ph4/ph8 (= 2 loads x 2 half-tiles in
// flight); final iteration skips forward stages and drains with vmcnt(0).
#define SYNC1 do { __builtin_amdgcn_s_barrier(); \
  asm volatile("s_waitcnt lgkmcnt(0)" ::: "memory"); \
  __builtin_amdgcn_sched_barrier(0); \
  __builtin_amdgcn_s_setprio(1); } while (0)
#define SYNC2 do { __builtin_amdgcn_s_setprio(0); \
  __builtin_amdgcn_s_barrier(); \
  __builtin_amdgcn_sched_barrier(0); } while (0)

template<int EPI, int MODE>
__global__ __launch_bounds__(512, 2)
void gemm8p(const unsigned short* __restrict__ Ag,
            const unsigned short* __restrict__ Bg,
            void* __restrict__ C,
            int K, int lda, int ldb, int ldc,
            size_t sAb, size_t sBb, size_t sCb) {
  extern __shared__ unsigned short lds8[];

  int gx = gridDim.x, gy = gridDim.y;
  int nwg = gx * gy * (int)gridDim.z;
  int lin = ((int)blockIdx.z * gy + (int)blockIdx.y) * gx + (int)blockIdx.x;
  int wg = swz_lin(lin, nwg);
  int bx = wg % gx;
  int rem = wg / gx;
  int by = rem % gy;
  int bz = rem / gy;

  int tmTile, tnBase;
  if (MODE == 1) {
    int t3 = bx;
    int tm3 = 0;
    while ((tm3 + 1) * (tm3 + 2) / 2 <= t3) tm3++;
    tmTile = tm3;
    tnBase = (t3 - tm3 * (tm3 + 1) / 2) * 256;
  } else {
    tmTile = by;
    tnBase = bx * 256;
  }
  int tm = tmTile * 256;

  Ag += (size_t)bz * sAb;
  Bg += (size_t)bz * sBb;
  float* Cf = (float*)C + (size_t)bz * sCb;
  unsigned short* Ch = (unsigned short*)C + (size_t)bz * sCb;

  int t = threadIdx.x;
  int lane = t & 63, wid = t >> 6;
  int wm = wid >> 2, wn = wid & 3;
  int lr = lane & 15, kof = (lane >> 4) * 8;
  int srow = lane >> 3, scol = (lane & 7) * 8;

  unsigned short* A0p = lds8;                 // buf0 A [256][64]
  unsigned short* B0p = lds8 + 16384;         // buf0 B
  unsigned short* A1p = lds8 + 32768;         // buf1 A
  unsigned short* B1p = lds8 + 49152;         // buf1 B

  f32x4 acc[8][4];
  f32x4 zero = {0.0f, 0.0f, 0.0f, 0.0f};
  #pragma unroll
  for (int m = 0; m < 8; ++m)
    #pragma unroll
    for (int n = 0; n < 4; ++n) acc[m][n] = zero;

  // stage one half-tile (128 rows x 64 cols): 2 gld16/thread
  auto stageA = [&](unsigned short* Ab, int kt, int h) {
    int k0 = kt * 64;
    #pragma unroll
    for (int i2 = 0; i2 < 2; ++i2) {
      int rr = h * 128 + wid * 16 + i2 * 8;
      gld16(Ag + (size_t)(tm + rr + srow) * lda + k0 + scol, Ab + rr * 64);
    }
  };
  auto stageB = [&](unsigned short* Bb, int kt, int h) {
    int k0 = kt * 64;
    #pragma unroll
    for (int i2 = 0; i2 < 2; ++i2) {
      int rr = h * 128 + wid * 16 + i2 * 8;
      gld16(Bg + (size_t)(tnBase + rr + srow) * ldb + k0 + scol, Bb + rr * 64);
    }
  };
  auto dsA = [&](const unsigned short* Ab, int mh, bf16x8 (&dst)[4][2]) {
    #pragma unroll
    for (int m4 = 0; m4 < 4; ++m4)
      #pragma unroll
      for (int k2 = 0; k2 < 2; ++k2)
        dst[m4][k2] = *(const bf16x8*)&Ab[(wm * 128 + (mh * 4 + m4) * 16 + lr) * 64 + k2 * 32 + kof];
  };
  auto dsB = [&](const unsigned short* Bb, int nh, bf16x8 (&dst)[2][2]) {
    #pragma unroll
    for (int n2 = 0; n2 < 2; ++n2)
      #pragma unroll
      for (int k2 = 0; k2 < 2; ++k2)
        dst[n2][k2] = *(const bf16x8*)&Bb[(wn * 64 + (nh * 2 + n2) * 16 + lr) * 64 + k2 * 32 + kof];
  };
  auto mfma16 = [&](bf16x8 (&a)[4][2], bf16x8 (&b)[2][2], int mh, int nh) {
    #pragma unroll
    for (int m4 = 0; m4 < 4; ++m4)
      #pragma unroll
      for (int n2 = 0; n2 < 2; ++n2)
        #pragma unroll
        for (int k2 = 0; k2 < 2; ++k2)
          acc[mh * 4 + m4][nh * 2 + n2] =
              __builtin_amdgcn_mfma_f32_16x16x32_bf16(a[m4][k2], b[n2][k2],
                                                      acc[mh * 4 + m4][nh * 2 + n2], 0, 0, 0);
  };

  int nk = K / 64, niter = nk / 2;

  // prologue: tile0 fully + B(1); leave B(1)'s 4 loads... (t0: 8, B1: 4)
  stageA(A0p, 0, 0); stageA(A0p, 0, 1);
  stageB(B0p, 0, 0); stageB(B0p, 0, 1);
  stageB(B1p, 1, 0); stageB(B1p, 1, 1);
  asm volatile("s_waitcnt vmcnt(4)" ::: "memory");
  __builtin_amdgcn_s_barrier();
  __builtin_amdgcn_sched_barrier(0);

  bf16x8 a0[4][2], a1[4][2], b0[2][2], b1[2][2];

  for (int it = 0; it < niter; ++it) {
    int a = 2 * it, b = a + 1;
    bool more = (it + 1 < niter);
    // ph1: Q(mh0,nh0) from buf0; stage A(b)h0 -> buf1.A
    dsA(A0p, 0, a0); dsB(B0p, 0, b0);
    stageA(A1p, b, 0);
    SYNC1; mfma16(a0, b0, 0, 0); SYNC2;
    // ph2: Q(mh0,nh1); stage A(b)h1
    dsB(B0p, 1, b1);
    stageA(A1p, b, 1);
    SYNC1; mfma16(a0, b1, 0, 1); SYNC2;
    // ph3: Q(mh1,nh1); stage B(a+2)h0 (buf0.B free after ph2)
    dsA(A0p, 1, a1);
    if (more) stageB(B0p, a + 2, 0);
    SYNC1; mfma16(a1, b1, 1, 1); SYNC2;
    // ph4: Q(mh1,nh0) (b0 kept); stage B(a+2)h1; vmcnt gate for tile b
    if (more) stageB(B0p, a + 2, 1);
    SYNC1; mfma16(a1, b0, 1, 0);
    __builtin_amdgcn_s_setprio(0);
    if (more) asm volatile("s_waitcnt vmcnt(4)" ::: "memory");
    else      asm volatile("s_waitcnt vmcnt(0)" ::: "memory");
    __builtin_amdgcn_s_barrier();
    __builtin_amdgcn_sched_barrier(0);
    // ph5: tile b from buf1; stage A(a+2)h0 (buf0.A free after ph3)
    dsA(A1p, 0, a0); dsB(B1p, 0, b0);
    if (more) stageA(A0p, a + 2, 0);
    SYNC1; mfma16(a0, b0, 0, 0); SYNC2;
    // ph6
    dsB(B1p, 1, b1);
    if (more) stageA(A0p, a + 2, 1);
    SYNC1; mfma16(a0, b1, 0, 1); SYNC2;
    // ph7: stage B(b+2)h0 (buf1.B free after ph6)
    dsA(A1p, 1, a1);
    if (more) stageB(B1p, b + 2, 0);
    SYNC1; mfma16(a1, b1, 1, 1); SYNC2;
    // ph8: vmcnt gate for tile a+2
    if (more) stageB(B1p, b + 2, 1);
    SYNC1; mfma16(a1, b0, 1, 0);
    __builtin_amdgcn_s_setprio(0);
    if (more) asm volatile("s_waitcnt vmcnt(4)" ::: "memory");
    else      asm volatile("s_waitcnt vmcnt(0)" ::: "memory");
    __builtin_amdgcn_s_barrier();
    __builtin_amdgcn_sched_barrier(0);
  }

  int rb0 = tm + wm * 128 + (lane >> 4) * 4;
  #pragma unroll
  for (int m = 0; m < 8; ++m) {
    #pragma unroll
    for (int n = 0; n < 4; ++n) {
      int col = tnBase + wn * 64 + n * 16 + lr;
      #pragma unroll
      for (int j = 0; j < 4; ++j) {
        int row = rb0 + m * 16 + j;
        float v = acc[m][n][j];
        size_t idx = (size_t)row * ldc + col;
        if constexpr (EPI == 1) Cf[idx] = v;
        else                    Ch[idx] = f2bf(v);
      }
    }
  }
}

// ---------------- fallback sentinel ----------------
__global__ void fill_kernel(float* out, int n, float v) {
  int i = blockIdx.x * blockDim.x + threadIdx.x;
  for (; i < n; i += gridDim.x * blockDim.x) out[i] = v;
}

extern "C" void kernel_launch(void* const* d_in, const int* in_sizes, int n_in,
                              void* d_out, int out_size, void* d_ws, size_t ws_size,
                              hipStream_t stream) {
  const float* x  = (const float*)d_in[0];
  const float* W1 = (const float*)d_in[1];
  const float* W2 = (const float*)d_in[2];
  const float* W3 = (const float*)d_in[3];
  float* out = (float*)d_out;

  char* ws = (char*)d_ws;
  size_t off = 0;
  auto alloc = [&](size_t bytes) -> char* {
    char* p = ws + off;
    off += (bytes + 255) & ~(size_t)255;
    return p;
  };

  unsigned short* zb  = (unsigned short*)alloc((size_t)MROWS * PDIM * 2);
  unsigned short* kvb = (unsigned short*)alloc((size_t)MROWS * 2 * PDIM * 2);
  unsigned short* vt  = (unsigned short*)alloc((size_t)BATCH * PDIM * L_SEQ * 2);
  unsigned short* ar  = (unsigned short*)alloc((size_t)MROWS * PDIM * 2);
  unsigned short* w3b = (unsigned short*)alloc((size_t)DOUT * PDIM * 2);
  size_t persist = off;

  char* scratch = ws + persist;
  size_t avail = (ws_size > persist) ? (ws_size - persist) : 0;

  size_t xbB  = ((size_t)MROWS * DIN * 2 + 255) & ~(size_t)255;
  size_t w1B  = ((size_t)PDIM * DIN * 2 + 255) & ~(size_t)255;
  size_t w2B  = ((size_t)2 * PDIM * PDIM * 2 + 255) & ~(size_t)255;
  size_t convNeed = xbB + w1B + w2B;

  size_t scores1 = ((size_t)L_SEQ * L_SEQ * 2 + 255) & ~(size_t)255; // 8MB bf16
  size_t per = scores1;

  if (avail < convNeed || avail < per) {
    float sentinel = 1.0e6f + (float)(ws_size >> 20);
    fill_kernel<<<512, 256, 0, stream>>>(out, out_size, sentinel);
    return;
  }

  int c = (int)(avail / per);
  if (c > BATCH) c = BATCH;
  int nch = (BATCH + c - 1) / c;
  c = (BATCH + nch - 1) / nch;

  unsigned short* xb  = (unsigned short*)(scratch);
  unsigned short* w1b = (unsigned short*)(scratch + xbB);
  unsigned short* w2b = (unsigned short*)(scratch + xbB + w1B);
  unsigned short* scores = (unsigned short*)(scratch);

  const float scaling = 0.04419417382415922f;  // 512^-0.5
  const int NTRI  = (L_SEQ / BM) * (L_SEQ / BM + 1) / 2;      // 136 (128-tiles)
  const int NTRI2 = (L_SEQ / 256) * (L_SEQ / 256 + 1) / 2;    // 36  (256-tiles)

  int big = 1;
  if (hipFuncSetAttribute(reinterpret_cast<const void*>(&gemm8p<0, 0>),
                          hipFuncAttributeMaxDynamicSharedMemorySize, 131072) != hipSuccess) big = 0;
  if (hipFuncSetAttribute(reinterpret_cast<const void*>(&gemm8p<1, 0>),
                          hipFuncAttributeMaxDynamicSharedMemorySize, 131072) != hipSuccess) big = 0;
  if (hipFuncSetAttribute(reinterpret_cast<const void*>(&gemm8p<0, 1>),
                          hipFuncAttributeMaxDynamicSharedMemorySize, 131072) != hipSuccess) big = 0;

  // converts
  convert_f32_bf16<<<2048, 256, 0, stream>>>(x,  xb,  (MROWS * DIN) / 4);
  convert_f32_bf16<<<512,  256, 0, stream>>>(W1, w1b, (PDIM * DIN) / 4);
  convert_f32_bf16<<<512,  256, 0, stream>>>(W2, w2b, (2 * PDIM * PDIM) / 4);
  convert_f32_bf16<<<512,  256, 0, stream>>>(W3, w3b, (DOUT * PDIM) / 4);

  // GEMM1: z = x @ W1^T (N=512 -> keep 128² kernel, 512 blocks)
  gemm_bt<0, 128><<<dim3(PDIM / 128, MROWS / BM, 1), 256, 0, stream>>>(
      xb, w1b, zb, zb, MROWS, PDIM, DIN, DIN, DIN, PDIM, 0, 0, 0, 0, 0);

  // GEMM2: kv = z @ W2^T -> 8-phase 256²
  if (big) {
    gemm8p<0, 0><<<dim3(2 * PDIM / 256, MROWS / 256, 1), 512, 131072, stream>>>(
        zb, w2b, kvb, PDIM, PDIM, PDIM, 2 * PDIM, 0, 0, 0);
  } else {
    gemm_bt<0, 128><<<dim3(2 * PDIM / 128, MROWS / BM, 1), 256, 0, stream>>>(
        zb, w2b, kvb, zb, MROWS, 2 * PDIM, PDIM, PDIM, PDIM, 2 * PDIM, 0, 0, 0, 0, 0);
  }

  // V transpose per batch
  transpose_v_kernel<<<dim3(L_SEQ / 32, PDIM / 32, BATCH), dim3(32, 8), 0, stream>>>(kvb, vt);

  for (int b0 = 0; b0 < BATCH; b0 += c) {
    int cb = (BATCH - b0 < c) ? (BATCH - b0) : c;

    // QK^T (bf16), causal lower-tri 256-tiles, 8-phase
    if (big) {
      gemm8p<0, 1><<<dim3(NTRI2, 1, cb), 512, 131072, stream>>>(
          zb + (size_t)b0 * PDIM, kvb + (size_t)b0 * 2 * PDIM, scores,
          PDIM, BATCH * PDIM, BATCH * 2 * PDIM, L_SEQ,
          (size_t)PDIM, (size_t)2 * PDIM, (size_t)L_SEQ * L_SEQ);
    } else {
      gemm_bt<0, 128><<<dim3(NTRI, 1, cb), 256, 0, stream>>>(
          zb + (size_t)b0 * PDIM, kvb + (size_t)b0 * 2 * PDIM, scores, zb,
          L_SEQ, L_SEQ, PDIM, BATCH * PDIM, BATCH * 2 * PDIM, L_SEQ,
          (size_t)PDIM, (size_t)2 * PDIM, (size_t)L_SEQ * L_SEQ, 0, 1);
    }

    softmax_causal<<<dim3(L_SEQ, 1, cb), 256, 0, stream>>>(
        scores, (size_t)L_SEQ * L_SEQ, scaling);

    // PV + residual (128²/BN=64 paired-row kernel)
    gemm_bt<2, 64><<<dim3(PDIM / 64, L_SEQ / BM / 2, cb), 256, 0, stream>>>(
        scores, vt + (size_t)b0 * PDIM * L_SEQ, ar + (size_t)b0 * PDIM,
        zb + (size_t)b0 * PDIM,
        L_SEQ, PDIM, L_SEQ, L_SEQ, L_SEQ, BATCH * PDIM,
        (size_t)L_SEQ * L_SEQ, (size_t)PDIM * L_SEQ, (size_t)PDIM, (size_t)PDIM, 2);
  }

  // GEMM3 -> 8-phase 256², fp32 out
  if (big) {
    gemm8p<1, 0><<<dim3(DOUT / 256, MROWS / 256, 1), 512, 131072, stream>>>(
        ar, w3b, out, PDIM, PDIM, PDIM, DOUT, 0, 0, 0);
  } else {
    gemm_bt<1, 128><<<dim3(DOUT / 128, MROWS / BM, 1), 256, 0, stream>>>(
        ar, w3b, out, zb, MROWS, DOUT, PDIM, PDIM, PDIM, DOUT, 0, 0, 0, 0, 0);
  }
}

// Round 10
// 228.232 us; speedup vs baseline: 1.0360x; 1.0360x over previous
//
#include <hip/hip_runtime.h>
#include <cstdint>
#include <cstddef>

#define L_SEQ 2048
#define BATCH 8
#define DIN   1024
#define PDIM  512
#define DOUT  1024
#define MROWS (L_SEQ * BATCH)   // 16384

typedef __attribute__((ext_vector_type(4))) float f32x4;
typedef __attribute__((ext_vector_type(8))) short bf16x8;

__device__ __forceinline__ unsigned short f2bf(float f) {
  union { float f; unsigned int u; } v; v.f = f;
  unsigned int u = v.u;
  unsigned int r = (u + 0x7FFFu + ((u >> 16) & 1u)) >> 16;
  return (unsigned short)r;
}
__device__ __forceinline__ float bf2f(unsigned short h) {
  union { unsigned int u; float f; } v; v.u = ((unsigned int)h) << 16;
  return v.f;
}

// async global->LDS, 16 bytes per lane; dest is wave-uniform base + lane*16
__device__ __forceinline__ void gld16(const unsigned short* g, unsigned short* l) {
  __builtin_amdgcn_global_load_lds(
      (const __attribute__((address_space(1))) void*)g,
      (__attribute__((address_space(3))) void*)l,
      16, 0, 0);
}

// T1: bijective XCD-chunked block remap (m204).
__device__ __forceinline__ int swz_lin(int lin, int nwg) {
  int q = nwg >> 3, r = nwg & 7;
  int xcd = lin & 7;
  int base = (xcd < r) ? xcd * (q + 1) : r * (q + 1) + (xcd - r) * q;
  return base + (lin >> 3);
}

// T2 LDS swizzle: logical 16B-chunk n of row r stored at position n ^ (r&7).
// Staging source col per lane (write side):  ((l&7) ^ (l>>3)) * 8
// Read col:                                  (col) ^ ((lane&7)<<3)

// ---------------- fp32 -> bf16 convert (vectorized) ----------------
__global__ void convert_f32_bf16(const float* __restrict__ in,
                                 unsigned short* __restrict__ out, int n4) {
  int i = blockIdx.x * blockDim.x + threadIdx.x;
  int stride = gridDim.x * blockDim.x;
  for (; i < n4; i += stride) {
    float4 v = reinterpret_cast<const float4*>(in)[i];
    ushort4 o;
    o.x = f2bf(v.x); o.y = f2bf(v.y); o.z = f2bf(v.z); o.w = f2bf(v.w);
    reinterpret_cast<ushort4*>(out)[i] = o;
  }
}

// ---------------- V transpose: kv[l][b][512+p] -> vt[b][p][l] ----------------
__global__ void transpose_v_kernel(const unsigned short* __restrict__ kv,
                                   unsigned short* __restrict__ vt) {
  __shared__ unsigned short tile[32][33];
  int b = blockIdx.z;
  int l0 = blockIdx.x * 32;
  int p0 = blockIdx.y * 32;
  const unsigned short* src = kv + (size_t)b * (2 * PDIM) + PDIM;
  unsigned short* dst = vt + (size_t)b * PDIM * L_SEQ;
  int tx = threadIdx.x, ty = threadIdx.y;
  #pragma unroll
  for (int r = ty; r < 32; r += 8)
    tile[r][tx] = src[(size_t)(l0 + r) * (BATCH * 2 * PDIM) + p0 + tx];
  __syncthreads();
  #pragma unroll
  for (int r = ty; r < 32; r += 8)
    dst[(size_t)(p0 + r) * L_SEQ + l0 + tx] = tile[tx][r];
}

// ---------------- row softmax with causal mask (bf16 in / in-place bf16 out) -
__global__ void softmax_causal(unsigned short* __restrict__ S,
                               size_t strideB, float scale) {
  __shared__ float buf[L_SEQ];
  __shared__ float red[4];
  int b = blockIdx.z;
  int i = blockIdx.x;                       // causal row index
  unsigned short* row = S + b * strideB + (size_t)i * L_SEQ;
  int t = threadIdx.x;
  int lane = t & 63, wid = t >> 6;

  float lmax = -3.0e38f;
  for (int j = t; j <= i; j += 256) {
    float v = bf2f(row[j]) * scale;
    buf[j] = v;
    lmax = fmaxf(lmax, v);
  }
  #pragma unroll
  for (int o = 32; o > 0; o >>= 1) lmax = fmaxf(lmax, __shfl_xor(lmax, o));
  if (lane == 0) red[wid] = lmax;
  __syncthreads();
  float m = fmaxf(fmaxf(red[0], red[1]), fmaxf(red[2], red[3]));

  float lsum = 0.0f;
  for (int j = t; j <= i; j += 256) {
    float e = __expf(buf[j] - m);
    buf[j] = e;
    lsum += e;
  }
  #pragma unroll
  for (int o = 32; o > 0; o >>= 1) lsum += __shfl_xor(lsum, o);
  __syncthreads();
  if (lane == 0) red[wid] = lsum;
  __syncthreads();
  float inv = 1.0f / (red[0] + red[1] + red[2] + red[3]);

  int jmax = ((i >> 7) + 1) << 7;
  for (int j = t; j < jmax; j += 256)
    row[j] = (j <= i) ? f2bf(buf[j] * inv) : (unsigned short)0;
}

// ---------------- bf16 MFMA GEMM 128²: 2-phase dbuf + T2 swizzle -----------
#define BM 128
#define BK 64

template<int EPI, int TBN>
__global__ __launch_bounds__(256)
void gemm_bt(const unsigned short* __restrict__ A,
             const unsigned short* __restrict__ B,
             void* __restrict__ C,
             const unsigned short* __restrict__ R,
             int M, int N, int K, int lda, int ldb, int ldc,
             size_t sAb, size_t sBb, size_t sCb, size_t sRb,
             int mode) {
  constexpr int MF   = (TBN == 128) ? 4 : 2;
  constexpr int BITS = TBN / 32;

  int gx = gridDim.x, gy = gridDim.y;
  int nwg = gx * gy * (int)gridDim.z;
  int lin = ((int)blockIdx.z * gy + (int)blockIdx.y) * gx + (int)blockIdx.x;
  int wg = swz_lin(lin, nwg);
  int bx = wg % gx;
  int rem = wg / gx;
  int by = rem % gy;
  int bz = rem / gy;

  A += (size_t)bz * sAb;
  B += (size_t)bz * sBb;
  R += (size_t)bz * sRb;
  float* Cf = (float*)C + (size_t)bz * sCb;
  unsigned short* Ch = (unsigned short*)C + (size_t)bz * sCb;

  __shared__ unsigned short As[2][BM * BK];
  __shared__ unsigned short Bs[2][TBN * BK];

  int t = threadIdx.x;
  int lane = t & 63;
  int wid = t >> 6;
  int wr = (TBN == 128) ? (wid >> 1) * 64 : wid * 32;
  int wc = (TBN == 128) ? (wid & 1) * 64 : 0;
  int lr = lane & 15;
  int kof = (lane >> 4) * 8;
  int srow = lane >> 3;                       // staging row in 8-row group
  int scol = ((lane & 7) ^ srow) * 8;         // T2 pre-swizzled global col
  int rxor = (lane & 7) << 3;                 // T2 read-side XOR

  int npass = (mode == 2) ? 2 : 1;

  for (int pass = 0; pass < npass; ++pass) {
    int tmTile, tnBase;
    if (mode == 1) {
      int t3 = bx;
      int tm3 = 0;
      while ((tm3 + 1) * (tm3 + 2) / 2 <= t3) tm3++;
      tmTile = tm3;
      tnBase = (t3 - tm3 * (tm3 + 1) / 2) * TBN;
    } else if (mode == 2) {
      int nt = M / BM;
      tmTile = pass ? (nt - 1 - by) : by;
      tnBase = bx * TBN;
    } else {
      tmTile = by;
      tnBase = bx * TBN;
    }
    int tm = tmTile * BM;
    int kEnd = (mode == 2) ? ((tm + BM) < K ? (tm + BM) : K) : K;
    int nk = kEnd / BK;

    f32x4 acc[MF][4];
    f32x4 zero = {0.0f, 0.0f, 0.0f, 0.0f};
    #pragma unroll
    for (int m = 0; m < MF; ++m)
      #pragma unroll
      for (int n = 0; n < 4; ++n) acc[m][n] = zero;

    auto stage = [&](int bi, int ks) {
      int k0 = ks * BK;
      #pragma unroll
      for (int it = 0; it < 4; ++it) {
        int r = wid * 32 + it * 8;
        gld16(A + (size_t)(tm + r + srow) * lda + k0 + scol, &As[bi][r * BK]);
      }
      #pragma unroll
      for (int it = 0; it < BITS; ++it) {
        int r = wid * (TBN / 4) + it * 8;
        gld16(B + (size_t)(tnBase + r + srow) * ldb + k0 + scol, &Bs[bi][r * BK]);
      }
    };

    stage(0, 0);
    for (int ks = 0; ks < nk; ++ks) {
      int bi = ks & 1;
      if (ks + 1 < nk) {
        stage(bi ^ 1, ks + 1);
        if constexpr (TBN == 128)
          asm volatile("s_waitcnt vmcnt(8)" ::: "memory");
        else
          asm volatile("s_waitcnt vmcnt(6)" ::: "memory");
      } else {
        asm volatile("s_waitcnt vmcnt(0)" ::: "memory");
      }
      __builtin_amdgcn_s_barrier();
      __builtin_amdgcn_sched_barrier(0);

      #pragma unroll
      for (int kk = 0; kk < BK; kk += 32) {
        bf16x8 af[MF], bfr[4];
        #pragma unroll
        for (int m = 0; m < MF; ++m)
          af[m] = *(const bf16x8*)&As[bi][(wr + m * 16 + lr) * BK + ((kk + kof) ^ rxor)];
        #pragma unroll
        for (int n = 0; n < 4; ++n)
          bfr[n] = *(const bf16x8*)&Bs[bi][(wc + n * 16 + lr) * BK + ((kk + kof) ^ rxor)];
        #pragma unroll
        for (int m = 0; m < MF; ++m)
          #pragma unroll
          for (int n = 0; n < 4; ++n)
            acc[m][n] = __builtin_amdgcn_mfma_f32_16x16x32_bf16(af[m], bfr[n], acc[m][n], 0, 0, 0);
      }
      asm volatile("" ::: "memory");
      __builtin_amdgcn_s_barrier();
      __builtin_amdgcn_sched_barrier(0);
    }

    int rb0 = tm + wr + (lane >> 4) * 4;
    #pragma unroll
    for (int m = 0; m < MF; ++m) {
      #pragma unroll
      for (int n = 0; n < 4; ++n) {
        int col = tnBase + wc + n * 16 + lr;
        #pragma unroll
        for (int j = 0; j < 4; ++j) {
          int row = rb0 + m * 16 + j;
          float v = acc[m][n][j];
          size_t idx = (size_t)row * ldc + col;
          if constexpr (EPI == 1) {
            Cf[idx] = v;
          } else if constexpr (EPI == 2) {
            Ch[idx] = f2bf(v + bf2f(R[idx]));
          } else {
            Ch[idx] = f2bf(v);
          }
        }
      }
    }
  }
}

// ---------------- bf16 MFMA GEMM 256²: 8-phase (T3+T4+T5) + T2 swizzle -----
#define SYNC1 do { __builtin_amdgcn_s_barrier(); \
  asm volatile("s_waitcnt lgkmcnt(0)" ::: "memory"); \
  __builtin_amdgcn_sched_barrier(0); \
  __builtin_amdgcn_s_setprio(1); } while (0)
#define SYNC2 do { __builtin_amdgcn_s_setprio(0); \
  __builtin_amdgcn_s_barrier(); \
  __builtin_amdgcn_sched_barrier(0); } while (0)

template<int EPI, int MODE>
__global__ __launch_bounds__(512, 2)
void gemm8p(const unsigned short* __restrict__ Ag,
            const unsigned short* __restrict__ Bg,
            void* __restrict__ C,
            int K, int lda, int ldb, int ldc,
            size_t sAb, size_t sBb, size_t sCb) {
  extern __shared__ unsigned short lds8[];

  int gx = gridDim.x, gy = gridDim.y;
  int nwg = gx * gy * (int)gridDim.z;
  int lin = ((int)blockIdx.z * gy + (int)blockIdx.y) * gx + (int)blockIdx.x;
  int wg = swz_lin(lin, nwg);
  int bx = wg % gx;
  int rem = wg / gx;
  int by = rem % gy;
  int bz = rem / gy;

  int tmTile, tnBase;
  if (MODE == 1) {
    int t3 = bx;
    int tm3 = 0;
    while ((tm3 + 1) * (tm3 + 2) / 2 <= t3) tm3++;
    tmTile = tm3;
    tnBase = (t3 - tm3 * (tm3 + 1) / 2) * 256;
  } else {
    tmTile = by;
    tnBase = bx * 256;
  }
  int tm = tmTile * 256;

  Ag += (size_t)bz * sAb;
  Bg += (size_t)bz * sBb;
  float* Cf = (float*)C + (size_t)bz * sCb;
  unsigned short* Ch = (unsigned short*)C + (size_t)bz * sCb;

  int t = threadIdx.x;
  int lane = t & 63, wid = t >> 6;
  int wm = wid >> 2, wn = wid & 3;
  int lr = lane & 15, kof = (lane >> 4) * 8;
  int srow = lane >> 3;
  int scol = ((lane & 7) ^ srow) * 8;         // T2 pre-swizzled global col
  int rxor = (lane & 7) << 3;                 // T2 read-side XOR

  unsigned short* A0p = lds8;                 // buf0 A [256][64]
  unsigned short* B0p = lds8 + 16384;         // buf0 B
  unsigned short* A1p = lds8 + 32768;         // buf1 A
  unsigned short* B1p = lds8 + 49152;         // buf1 B

  f32x4 acc[8][4];
  f32x4 zero = {0.0f, 0.0f, 0.0f, 0.0f};
  #pragma unroll
  for (int m = 0; m < 8; ++m)
    #pragma unroll
    for (int n = 0; n < 4; ++n) acc[m][n] = zero;

  auto stageA = [&](unsigned short* Ab, int kt, int h) {
    int k0 = kt * 64;
    #pragma unroll
    for (int i2 = 0; i2 < 2; ++i2) {
      int rr = h * 128 + wid * 16 + i2 * 8;
      gld16(Ag + (size_t)(tm + rr + srow) * lda + k0 + scol, Ab + rr * 64);
    }
  };
  auto stageB = [&](unsigned short* Bb, int kt, int h) {
    int k0 = kt * 64;
    #pragma unroll
    for (int i2 = 0; i2 < 2; ++i2) {
      int rr = h * 128 + wid * 16 + i2 * 8;
      gld16(Bg + (size_t)(tnBase + rr + srow) * ldb + k0 + scol, Bb + rr * 64);
    }
  };
  auto dsA = [&](const unsigned short* Ab, int mh, bf16x8 (&dst)[4][2]) {
    #pragma unroll
    for (int m4 = 0; m4 < 4; ++m4)
      #pragma unroll
      for (int k2 = 0; k2 < 2; ++k2)
        dst[m4][k2] = *(const bf16x8*)&Ab[(wm * 128 + (mh * 4 + m4) * 16 + lr) * 64 + ((k2 * 32 + kof) ^ rxor)];
  };
  auto dsB = [&](const unsigned short* Bb, int nh, bf16x8 (&dst)[2][2]) {
    #pragma unroll
    for (int n2 = 0; n2 < 2; ++n2)
      #pragma unroll
      for (int k2 = 0; k2 < 2; ++k2)
        dst[n2][k2] = *(const bf16x8*)&Bb[(wn * 64 + (nh * 2 + n2) * 16 + lr) * 64 + ((k2 * 32 + kof) ^ rxor)];
  };
  auto mfma16 = [&](bf16x8 (&a)[4][2], bf16x8 (&b)[2][2], int mh, int nh) {
    #pragma unroll
    for (int m4 = 0; m4 < 4; ++m4)
      #pragma unroll
      for (int n2 = 0; n2 < 2; ++n2)
        #pragma unroll
        for (int k2 = 0; k2 < 2; ++k2)
          acc[mh * 4 + m4][nh * 2 + n2] =
              __builtin_amdgcn_mfma_f32_16x16x32_bf16(a[m4][k2], b[n2][k2],
                                                      acc[mh * 4 + m4][nh * 2 + n2], 0, 0, 0);
  };

  int nk = K / 64, niter = nk / 2;

  // prologue: tile0 fully + B(1); vmcnt(4) leaves B(1)'s 4 loads in flight
  stageA(A0p, 0, 0); stageA(A0p, 0, 1);
  stageB(B0p, 0, 0); stageB(B0p, 0, 1);
  stageB(B1p, 1, 0); stageB(B1p, 1, 1);
  asm volatile("s_waitcnt vmcnt(4)" ::: "memory");
  __builtin_amdgcn_s_barrier();
  __builtin_amdgcn_sched_barrier(0);

  bf16x8 a0[4][2], a1[4][2], b0[2][2], b1[2][2];

  for (int it = 0; it < niter; ++it) {
    int a = 2 * it, b = a + 1;
    bool more = (it + 1 < niter);
    // ph1: Q(mh0,nh0) from buf0; stage A(b)h0 -> buf1.A
    dsA(A0p, 0, a0); dsB(B0p, 0, b0);
    stageA(A1p, b, 0);
    SYNC1; mfma16(a0, b0, 0, 0); SYNC2;
    // ph2: Q(mh0,nh1); stage A(b)h1
    dsB(B0p, 1, b1);
    stageA(A1p, b, 1);
    SYNC1; mfma16(a0, b1, 0, 1); SYNC2;
    // ph3: Q(mh1,nh1); stage B(a+2)h0 (buf0.B free after ph2)
    dsA(A0p, 1, a1);
    if (more) stageB(B0p, a + 2, 0);
    SYNC1; mfma16(a1, b1, 1, 1); SYNC2;
    // ph4: Q(mh1,nh0) (b0 kept); stage B(a+2)h1; vmcnt gate for tile b
    if (more) stageB(B0p, a + 2, 1);
    SYNC1; mfma16(a1, b0, 1, 0);
    __builtin_amdgcn_s_setprio(0);
    if (more) asm volatile("s_waitcnt vmcnt(4)" ::: "memory");
    else      asm volatile("s_waitcnt vmcnt(0)" ::: "memory");
    __builtin_amdgcn_s_barrier();
    __builtin_amdgcn_sched_barrier(0);
    // ph5: tile b from buf1; stage A(a+2)h0 (buf0.A free after ph3)
    dsA(A1p, 0, a0); dsB(B1p, 0, b0);
    if (more) stageA(A0p, a + 2, 0);
    SYNC1; mfma16(a0, b0, 0, 0); SYNC2;
    // ph6
    dsB(B1p, 1, b1);
    if (more) stageA(A0p, a + 2, 1);
    SYNC1; mfma16(a0, b1, 0, 1); SYNC2;
    // ph7: stage B(b+2)h0 (buf1.B free after ph6)
    dsA(A1p, 1, a1);
    if (more) stageB(B1p, b + 2, 0);
    SYNC1; mfma16(a1, b1, 1, 1); SYNC2;
    // ph8: vmcnt gate for tile a+2
    if (more) stageB(B1p, b + 2, 1);
    SYNC1; mfma16(a1, b0, 1, 0);
    __builtin_amdgcn_s_setprio(0);
    if (more) asm volatile("s_waitcnt vmcnt(4)" ::: "memory");
    else      asm volatile("s_waitcnt vmcnt(0)" ::: "memory");
    __builtin_amdgcn_s_barrier();
    __builtin_amdgcn_sched_barrier(0);
  }

  int rb0 = tm + wm * 128 + (lane >> 4) * 4;
  #pragma unroll
  for (int m = 0; m < 8; ++m) {
    #pragma unroll
    for (int n = 0; n < 4; ++n) {
      int col = tnBase + wn * 64 + n * 16 + lr;
      #pragma unroll
      for (int j = 0; j < 4; ++j) {
        int row = rb0 + m * 16 + j;
        float v = acc[m][n][j];
        size_t idx = (size_t)row * ldc + col;
        if constexpr (EPI == 1) Cf[idx] = v;
        else                    Ch[idx] = f2bf(v);
      }
    }
  }
}

// ---------------- fallback sentinel ----------------
__global__ void fill_kernel(float* out, int n, float v) {
  int i = blockIdx.x * blockDim.x + threadIdx.x;
  for (; i < n; i += gridDim.x * blockDim.x) out[i] = v;
}

extern "C" void kernel_launch(void* const* d_in, const int* in_sizes, int n_in,
                              void* d_out, int out_size, void* d_ws, size_t ws_size,
                              hipStream_t stream) {
  const float* x  = (const float*)d_in[0];
  const float* W1 = (const float*)d_in[1];
  const float* W2 = (const float*)d_in[2];
  const float* W3 = (const float*)d_in[3];
  float* out = (float*)d_out;

  char* ws = (char*)d_ws;
  size_t off = 0;
  auto alloc = [&](size_t bytes) -> char* {
    char* p = ws + off;
    off += (bytes + 255) & ~(size_t)255;
    return p;
  };

  unsigned short* zb  = (unsigned short*)alloc((size_t)MROWS * PDIM * 2);
  unsigned short* kvb = (unsigned short*)alloc((size_t)MROWS * 2 * PDIM * 2);
  unsigned short* vt  = (unsigned short*)alloc((size_t)BATCH * PDIM * L_SEQ * 2);
  unsigned short* ar  = (unsigned short*)alloc((size_t)MROWS * PDIM * 2);
  unsigned short* w3b = (unsigned short*)alloc((size_t)DOUT * PDIM * 2);
  size_t persist = off;

  char* scratch = ws + persist;
  size_t avail = (ws_size > persist) ? (ws_size - persist) : 0;

  size_t xbB  = ((size_t)MROWS * DIN * 2 + 255) & ~(size_t)255;
  size_t w1B  = ((size_t)PDIM * DIN * 2 + 255) & ~(size_t)255;
  size_t w2B  = ((size_t)2 * PDIM * PDIM * 2 + 255) & ~(size_t)255;
  size_t convNeed = xbB + w1B + w2B;

  size_t scores1 = ((size_t)L_SEQ * L_SEQ * 2 + 255) & ~(size_t)255; // 8MB bf16
  size_t per = scores1;

  if (avail < convNeed || avail < per) {
    float sentinel = 1.0e6f + (float)(ws_size >> 20);
    fill_kernel<<<512, 256, 0, stream>>>(out, out_size, sentinel);
    return;
  }

  int c = (int)(avail / per);
  if (c > BATCH) c = BATCH;
  int nch = (BATCH + c - 1) / c;
  c = (BATCH + nch - 1) / nch;

  unsigned short* xb  = (unsigned short*)(scratch);
  unsigned short* w1b = (unsigned short*)(scratch + xbB);
  unsigned short* w2b = (unsigned short*)(scratch + xbB + w1B);
  unsigned short* scores = (unsigned short*)(scratch);

  const float scaling = 0.04419417382415922f;  // 512^-0.5
  const int NTRI  = (L_SEQ / BM) * (L_SEQ / BM + 1) / 2;      // 136 (128-tiles)
  const int NTRI2 = (L_SEQ / 256) * (L_SEQ / 256 + 1) / 2;    // 36  (256-tiles)

  int big = 1;
  if (hipFuncSetAttribute(reinterpret_cast<const void*>(&gemm8p<0, 0>),
                          hipFuncAttributeMaxDynamicSharedMemorySize, 131072) != hipSuccess) big = 0;
  if (hipFuncSetAttribute(reinterpret_cast<const void*>(&gemm8p<1, 0>),
                          hipFuncAttributeMaxDynamicSharedMemorySize, 131072) != hipSuccess) big = 0;
  if (hipFuncSetAttribute(reinterpret_cast<const void*>(&gemm8p<0, 1>),
                          hipFuncAttributeMaxDynamicSharedMemorySize, 131072) != hipSuccess) big = 0;

  // converts
  convert_f32_bf16<<<2048, 256, 0, stream>>>(x,  xb,  (MROWS * DIN) / 4);
  convert_f32_bf16<<<512,  256, 0, stream>>>(W1, w1b, (PDIM * DIN) / 4);
  convert_f32_bf16<<<512,  256, 0, stream>>>(W2, w2b, (2 * PDIM * PDIM) / 4);
  convert_f32_bf16<<<512,  256, 0, stream>>>(W3, w3b, (DOUT * PDIM) / 4);

  // GEMM1: z = x @ W1^T (N=512 -> keep 128² kernel, 512 blocks)
  gemm_bt<0, 128><<<dim3(PDIM / 128, MROWS / BM, 1), 256, 0, stream>>>(
      xb, w1b, zb, zb, MROWS, PDIM, DIN, DIN, DIN, PDIM, 0, 0, 0, 0, 0);

  // GEMM2: kv = z @ W2^T -> 8-phase 256²
  if (big) {
    gemm8p<0, 0><<<dim3(2 * PDIM / 256, MROWS / 256, 1), 512, 131072, stream>>>(
        zb, w2b, kvb, PDIM, PDIM, PDIM, 2 * PDIM, 0, 0, 0);
  } else {
    gemm_bt<0, 128><<<dim3(2 * PDIM / 128, MROWS / BM, 1), 256, 0, stream>>>(
        zb, w2b, kvb, zb, MROWS, 2 * PDIM, PDIM, PDIM, PDIM, 2 * PDIM, 0, 0, 0, 0, 0);
  }

  // V transpose per batch
  transpose_v_kernel<<<dim3(L_SEQ / 32, PDIM / 32, BATCH), dim3(32, 8), 0, stream>>>(kvb, vt);

  for (int b0 = 0; b0 < BATCH; b0 += c) {
    int cb = (BATCH - b0 < c) ? (BATCH - b0) : c;

    // QK^T (bf16), causal lower-tri 256-tiles, 8-phase
    if (big) {
      gemm8p<0, 1><<<dim3(NTRI2, 1, cb), 512, 131072, stream>>>(
          zb + (size_t)b0 * PDIM, kvb + (size_t)b0 * 2 * PDIM, scores,
          PDIM, BATCH * PDIM, BATCH * 2 * PDIM, L_SEQ,
          (size_t)PDIM, (size_t)2 * PDIM, (size_t)L_SEQ * L_SEQ);
    } else {
      gemm_bt<0, 128><<<dim3(NTRI, 1, cb), 256, 0, stream>>>(
          zb + (size_t)b0 * PDIM, kvb + (size_t)b0 * 2 * PDIM, scores, zb,
          L_SEQ, L_SEQ, PDIM, BATCH * PDIM, BATCH * 2 * PDIM, L_SEQ,
          (size_t)PDIM, (size_t)2 * PDIM, (size_t)L_SEQ * L_SEQ, 0, 1);
    }

    softmax_causal<<<dim3(L_SEQ, 1, cb), 256, 0, stream>>>(
        scores, (size_t)L_SEQ * L_SEQ, scaling);

    // PV + residual (128²/BN=64 paired-row kernel)
    gemm_bt<2, 64><<<dim3(PDIM / 64, L_SEQ / BM / 2, cb), 256, 0, stream>>>(
        scores, vt + (size_t)b0 * PDIM * L_SEQ, ar + (size_t)b0 * PDIM,
        zb + (size_t)b0 * PDIM,
        L_SEQ, PDIM, L_SEQ, L_SEQ, L_SEQ, BATCH * PDIM,
        (size_t)L_SEQ * L_SEQ, (size_t)PDIM * L_SEQ, (size_t)PDIM, (size_t)PDIM, 2);
  }

  // GEMM3 -> 8-phase 256², fp32 out
  if (big) {
    gemm8p<1, 0><<<dim3(DOUT / 256, MROWS / 256, 1), 512, 131072, stream>>>(
        ar, w3b, out, PDIM, PDIM, PDIM, DOUT, 0, 0, 0);
  } else {
    gemm_bt<1, 128><<<dim3(DOUT / 128, MROWS / BM, 1), 256, 0, stream>>>(
        ar, w3b, out, zb, MROWS, DOUT, PDIM, PDIM, PDIM, DOUT, 0, 0, 0, 0, 0);
  }
}

// Round 11
// 197.815 us; speedup vs baseline: 1.1953x; 1.1538x over previous
//
#include <hip/hip_runtime.h>
#include <cstdint>
#include <cstddef>

#define L_SEQ 2048
#define BATCH 8
#define DIN   1024
#define PDIM  512
#define DOUT  1024
#define MROWS (L_SEQ * BATCH)   // 16384

typedef __attribute__((ext_vector_type(4))) float f32x4;
typedef __attribute__((ext_vector_type(8))) short bf16x8;

__device__ __forceinline__ unsigned short f2bf(float f) {
  union { float f; unsigned int u; } v; v.f = f;
  unsigned int u = v.u;
  unsigned int r = (u + 0x7FFFu + ((u >> 16) & 1u)) >> 16;
  return (unsigned short)r;
}
__device__ __forceinline__ float bf2f(unsigned short h) {
  union { unsigned int u; float f; } v; v.u = ((unsigned int)h) << 16;
  return v.f;
}

// async global->LDS, 16 bytes per lane; dest is wave-uniform base + lane*16
__device__ __forceinline__ void gld16(const unsigned short* g, unsigned short* l) {
  __builtin_amdgcn_global_load_lds(
      (const __attribute__((address_space(1))) void*)g,
      (__attribute__((address_space(3))) void*)l,
      16, 0, 0);
}

// T1: bijective XCD-chunked block remap (m204).
__device__ __forceinline__ int swz_lin(int lin, int nwg) {
  int q = nwg >> 3, r = nwg & 7;
  int xcd = lin & 7;
  int base = (xcd < r) ? xcd * (q + 1) : r * (q + 1) + (xcd - r) * q;
  return base + (lin >> 3);
}

// T2 LDS swizzle: logical 16B-chunk n of row r stored at position n ^ (r&7).
// Write side folds into the per-lane GLOBAL source column (gld16 dest linear);
// read side XORs the chunk index. Same involution both sides (rule #21).

// ---------------- fp32 -> bf16 convert (vectorized) ----------------
__global__ void convert_f32_bf16(const float* __restrict__ in,
                                 unsigned short* __restrict__ out, int n4) {
  int i = blockIdx.x * blockDim.x + threadIdx.x;
  int stride = gridDim.x * blockDim.x;
  for (; i < n4; i += stride) {
    float4 v = reinterpret_cast<const float4*>(in)[i];
    ushort4 o;
    o.x = f2bf(v.x); o.y = f2bf(v.y); o.z = f2bf(v.z); o.w = f2bf(v.w);
    reinterpret_cast<ushort4*>(out)[i] = o;
  }
}

// ---------------- V transpose: kv[l][b][512+p] -> vt[b][p][l] ----------------
__global__ void transpose_v_kernel(const unsigned short* __restrict__ kv,
                                   unsigned short* __restrict__ vt) {
  __shared__ unsigned short tile[32][33];
  int b = blockIdx.z;
  int l0 = blockIdx.x * 32;
  int p0 = blockIdx.y * 32;
  const unsigned short* src = kv + (size_t)b * (2 * PDIM) + PDIM;
  unsigned short* dst = vt + (size_t)b * PDIM * L_SEQ;
  int tx = threadIdx.x, ty = threadIdx.y;
  #pragma unroll
  for (int r = ty; r < 32; r += 8)
    tile[r][tx] = src[(size_t)(l0 + r) * (BATCH * 2 * PDIM) + p0 + tx];
  __syncthreads();
  #pragma unroll
  for (int r = ty; r < 32; r += 8)
    dst[(size_t)(p0 + r) * L_SEQ + l0 + tx] = tile[tx][r];
}

// ---------------- row softmax with causal mask (bf16 in / in-place bf16 out) -
__global__ void softmax_causal(unsigned short* __restrict__ S,
                               size_t strideB, float scale) {
  __shared__ float buf[L_SEQ];
  __shared__ float red[4];
  int b = blockIdx.z;
  int i = blockIdx.x;                       // causal row index
  unsigned short* row = S + b * strideB + (size_t)i * L_SEQ;
  int t = threadIdx.x;
  int lane = t & 63, wid = t >> 6;

  float lmax = -3.0e38f;
  for (int j = t; j <= i; j += 256) {
    float v = bf2f(row[j]) * scale;
    buf[j] = v;
    lmax = fmaxf(lmax, v);
  }
  #pragma unroll
  for (int o = 32; o > 0; o >>= 1) lmax = fmaxf(lmax, __shfl_xor(lmax, o));
  if (lane == 0) red[wid] = lmax;
  __syncthreads();
  float m = fmaxf(fmaxf(red[0], red[1]), fmaxf(red[2], red[3]));

  float lsum = 0.0f;
  for (int j = t; j <= i; j += 256) {
    float e = __expf(buf[j] - m);
    buf[j] = e;
    lsum += e;
  }
  #pragma unroll
  for (int o = 32; o > 0; o >>= 1) lsum += __shfl_xor(lsum, o);
  __syncthreads();
  if (lane == 0) red[wid] = lsum;
  __syncthreads();
  float inv = 1.0f / (red[0] + red[1] + red[2] + red[3]);

  // PV's causal K-limit reads exactly up to the next 128-aligned boundary
  int jmax = ((i >> 7) + 1) << 7;
  for (int j = t; j < jmax; j += 256)
    row[j] = (j <= i) ? f2bf(buf[j] * inv) : (unsigned short)0;
}

// ---------------- bf16 MFMA GEMM 128²: 2-phase dbuf + T1 + T2 --------------
// EPI: 0 = store bf16, 1 = store fp32, 2 = store bf16 with residual add (R)
// mode: 0 = plain;
//       1 = causal lower-tri tile enumeration via bx (QK^T);
//       3 = plain grid with causal K-limit, row-tiles mapped DESCENDING in
//           work (tmTile = nt-1-by) so heavy blocks start first (PV).
#define BM 128
#define BK 64

template<int EPI, int TBN>
__global__ __launch_bounds__(256)
void gemm_bt(const unsigned short* __restrict__ A,
             const unsigned short* __restrict__ B,
             void* __restrict__ C,
             const unsigned short* __restrict__ R,
             int M, int N, int K, int lda, int ldb, int ldc,
             size_t sAb, size_t sBb, size_t sCb, size_t sRb,
             int mode) {
  constexpr int MF   = (TBN == 128) ? 4 : 2;
  constexpr int BITS = TBN / 32;

  int gx = gridDim.x, gy = gridDim.y;
  int nwg = gx * gy * (int)gridDim.z;
  int lin = ((int)blockIdx.z * gy + (int)blockIdx.y) * gx + (int)blockIdx.x;
  int wg = swz_lin(lin, nwg);
  int bx = wg % gx;
  int rem = wg / gx;
  int by = rem % gy;
  int bz = rem / gy;

  A += (size_t)bz * sAb;
  B += (size_t)bz * sBb;
  R += (size_t)bz * sRb;
  float* Cf = (float*)C + (size_t)bz * sCb;
  unsigned short* Ch = (unsigned short*)C + (size_t)bz * sCb;

  __shared__ unsigned short As[2][BM * BK];
  __shared__ unsigned short Bs[2][TBN * BK];

  int t = threadIdx.x;
  int lane = t & 63;
  int wid = t >> 6;
  int wr = (TBN == 128) ? (wid >> 1) * 64 : wid * 32;
  int wc = (TBN == 128) ? (wid & 1) * 64 : 0;
  int lr = lane & 15;
  int kof = (lane >> 4) * 8;
  int srow = lane >> 3;                       // staging row in 8-row group
  int scol = ((lane & 7) ^ srow) * 8;         // T2 pre-swizzled global col
  int rxor = (lane & 7) << 3;                 // T2 read-side XOR

  int tmTile, tnBase;
  if (mode == 1) {
    int t3 = bx;                              // linear lower-tri index
    int tm3 = 0;
    while ((tm3 + 1) * (tm3 + 2) / 2 <= t3) tm3++;
    tmTile = tm3;
    tnBase = (t3 - tm3 * (tm3 + 1) / 2) * TBN;
  } else if (mode == 3) {
    tmTile = (M / BM - 1) - by;               // descending work order
    tnBase = bx * TBN;
  } else {
    tmTile = by;
    tnBase = bx * TBN;
  }
  int tm = tmTile * BM;
  int kEnd = (mode == 3) ? ((tm + BM) < K ? (tm + BM) : K) : K;
  int nk = kEnd / BK;

  f32x4 acc[MF][4];
  f32x4 zero = {0.0f, 0.0f, 0.0f, 0.0f};
  #pragma unroll
  for (int m = 0; m < MF; ++m)
    #pragma unroll
    for (int n = 0; n < 4; ++n) acc[m][n] = zero;

  auto stage = [&](int bi, int ks) {
    int k0 = ks * BK;
    #pragma unroll
    for (int it = 0; it < 4; ++it) {
      int r = wid * 32 + it * 8;
      gld16(A + (size_t)(tm + r + srow) * lda + k0 + scol, &As[bi][r * BK]);
    }
    #pragma unroll
    for (int it = 0; it < BITS; ++it) {
      int r = wid * (TBN / 4) + it * 8;
      gld16(B + (size_t)(tnBase + r + srow) * ldb + k0 + scol, &Bs[bi][r * BK]);
    }
  };

  stage(0, 0);
  for (int ks = 0; ks < nk; ++ks) {
    int bi = ks & 1;
    if (ks + 1 < nk) {
      stage(bi ^ 1, ks + 1);
      if constexpr (TBN == 128)
        asm volatile("s_waitcnt vmcnt(8)" ::: "memory");
      else
        asm volatile("s_waitcnt vmcnt(6)" ::: "memory");
    } else {
      asm volatile("s_waitcnt vmcnt(0)" ::: "memory");
    }
    __builtin_amdgcn_s_barrier();
    __builtin_amdgcn_sched_barrier(0);

    #pragma unroll
    for (int kk = 0; kk < BK; kk += 32) {
      bf16x8 af[MF], bfr[4];
      #pragma unroll
      for (int m = 0; m < MF; ++m)
        af[m] = *(const bf16x8*)&As[bi][(wr + m * 16 + lr) * BK + ((kk + kof) ^ rxor)];
      #pragma unroll
      for (int n = 0; n < 4; ++n)
        bfr[n] = *(const bf16x8*)&Bs[bi][(wc + n * 16 + lr) * BK + ((kk + kof) ^ rxor)];
      #pragma unroll
      for (int m = 0; m < MF; ++m)
        #pragma unroll
        for (int n = 0; n < 4; ++n)
          acc[m][n] = __builtin_amdgcn_mfma_f32_16x16x32_bf16(af[m], bfr[n], acc[m][n], 0, 0, 0);
    }
    asm volatile("" ::: "memory");
    __builtin_amdgcn_s_barrier();
    __builtin_amdgcn_sched_barrier(0);
  }

  int rb0 = tm + wr + (lane >> 4) * 4;       // C/D: col=lane&15, row=(lane>>4)*4+j
  #pragma unroll
  for (int m = 0; m < MF; ++m) {
    #pragma unroll
    for (int n = 0; n < 4; ++n) {
      int col = tnBase + wc + n * 16 + lr;
      #pragma unroll
      for (int j = 0; j < 4; ++j) {
        int row = rb0 + m * 16 + j;
        float v = acc[m][n][j];
        size_t idx = (size_t)row * ldc + col;
        if constexpr (EPI == 1) {
          Cf[idx] = v;
        } else if constexpr (EPI == 2) {
          Ch[idx] = f2bf(v + bf2f(R[idx]));
        } else {
          Ch[idx] = f2bf(v);
        }
      }
    }
  }
}

// ---------------- fallback sentinel ----------------
__global__ void fill_kernel(float* out, int n, float v) {
  int i = blockIdx.x * blockDim.x + threadIdx.x;
  for (; i < n; i += gridDim.x * blockDim.x) out[i] = v;
}

extern "C" void kernel_launch(void* const* d_in, const int* in_sizes, int n_in,
                              void* d_out, int out_size, void* d_ws, size_t ws_size,
                              hipStream_t stream) {
  const float* x  = (const float*)d_in[0];
  const float* W1 = (const float*)d_in[1];
  const float* W2 = (const float*)d_in[2];
  const float* W3 = (const float*)d_in[3];
  float* out = (float*)d_out;

  char* ws = (char*)d_ws;
  size_t off = 0;
  auto alloc = [&](size_t bytes) -> char* {
    char* p = ws + off;
    off += (bytes + 255) & ~(size_t)255;
    return p;
  };

  unsigned short* zb  = (unsigned short*)alloc((size_t)MROWS * PDIM * 2);
  unsigned short* kvb = (unsigned short*)alloc((size_t)MROWS * 2 * PDIM * 2);
  unsigned short* vt  = (unsigned short*)alloc((size_t)BATCH * PDIM * L_SEQ * 2);
  unsigned short* ar  = (unsigned short*)alloc((size_t)MROWS * PDIM * 2);
  unsigned short* w3b = (unsigned short*)alloc((size_t)DOUT * PDIM * 2);
  size_t persist = off;

  char* scratch = ws + persist;
  size_t avail = (ws_size > persist) ? (ws_size - persist) : 0;

  size_t xbB  = ((size_t)MROWS * DIN * 2 + 255) & ~(size_t)255;
  size_t w1B  = ((size_t)PDIM * DIN * 2 + 255) & ~(size_t)255;
  size_t w2B  = ((size_t)2 * PDIM * PDIM * 2 + 255) & ~(size_t)255;
  size_t convNeed = xbB + w1B + w2B;

  size_t scores1 = ((size_t)L_SEQ * L_SEQ * 2 + 255) & ~(size_t)255; // 8MB bf16
  size_t per = scores1;

  if (avail < convNeed || avail < per) {
    float sentinel = 1.0e6f + (float)(ws_size >> 20);
    fill_kernel<<<512, 256, 0, stream>>>(out, out_size, sentinel);
    return;
  }

  int c = (int)(avail / per);
  if (c > BATCH) c = BATCH;
  int nch = (BATCH + c - 1) / c;
  c = (BATCH + nch - 1) / nch;

  unsigned short* xb  = (unsigned short*)(scratch);
  unsigned short* w1b = (unsigned short*)(scratch + xbB);
  unsigned short* w2b = (unsigned short*)(scratch + xbB + w1B);
  unsigned short* scores = (unsigned short*)(scratch);

  const float scaling = 0.04419417382415922f;  // 512^-0.5
  const int NTRI = (L_SEQ / BM) * (L_SEQ / BM + 1) / 2;   // 136 lower-tri tiles

  // converts
  convert_f32_bf16<<<2048, 256, 0, stream>>>(x,  xb,  (MROWS * DIN) / 4);
  convert_f32_bf16<<<512,  256, 0, stream>>>(W1, w1b, (PDIM * DIN) / 4);
  convert_f32_bf16<<<512,  256, 0, stream>>>(W2, w2b, (2 * PDIM * PDIM) / 4);
  convert_f32_bf16<<<512,  256, 0, stream>>>(W3, w3b, (DOUT * PDIM) / 4);

  // GEMM1: z = x @ W1^T   [16384,1024]x[512,1024] -> [16384,512] bf16
  gemm_bt<0, 128><<<dim3(PDIM / 128, MROWS / BM, 1), 256, 0, stream>>>(
      xb, w1b, zb, zb, MROWS, PDIM, DIN, DIN, DIN, PDIM, 0, 0, 0, 0, 0);

  // GEMM2: kv = z @ W2^T  [16384,512]x[1024,512] -> [16384,1024] bf16
  gemm_bt<0, 128><<<dim3(2 * PDIM / 128, MROWS / BM, 1), 256, 0, stream>>>(
      zb, w2b, kvb, zb, MROWS, 2 * PDIM, PDIM, PDIM, PDIM, 2 * PDIM, 0, 0, 0, 0, 0);

  // V transpose per batch: vt[b][p][l]
  transpose_v_kernel<<<dim3(L_SEQ / 32, PDIM / 32, BATCH), dim3(32, 8), 0, stream>>>(kvb, vt);

  // ---- chunked attention (c==8 expected: single pass) ----
  for (int b0 = 0; b0 < BATCH; b0 += c) {
    int cb = (BATCH - b0 < c) ? (BATCH - b0) : c;

    // scores[z] = Q @ K^T (bf16), triangular tile enumeration (mode 1)
    gemm_bt<0, 128><<<dim3(NTRI, 1, cb), 256, 0, stream>>>(
        zb + (size_t)b0 * PDIM, kvb + (size_t)b0 * 2 * PDIM, scores, zb,
        L_SEQ, L_SEQ, PDIM, BATCH * PDIM, BATCH * 2 * PDIM, L_SEQ,
        (size_t)PDIM, (size_t)2 * PDIM, (size_t)L_SEQ * L_SEQ, 0, 1);

    softmax_causal<<<dim3(L_SEQ, 1, cb), 256, 0, stream>>>(
        scores, (size_t)L_SEQ * L_SEQ, scaling);

    // attn_out + residual -> ar (bf16): unpaired causal row-tiles (mode 3),
    // BN=64, grid 8x16 per batch -> 1024 blocks at cb=8
    gemm_bt<2, 64><<<dim3(PDIM / 64, L_SEQ / BM, cb), 256, 0, stream>>>(
        scores, vt + (size_t)b0 * PDIM * L_SEQ, ar + (size_t)b0 * PDIM,
        zb + (size_t)b0 * PDIM,
        L_SEQ, PDIM, L_SEQ, L_SEQ, L_SEQ, BATCH * PDIM,
        (size_t)L_SEQ * L_SEQ, (size_t)PDIM * L_SEQ, (size_t)PDIM, (size_t)PDIM, 3);
  }

  // GEMM3: out = (attn + residual) @ W3^T -> fp32 d_out
  gemm_bt<1, 128><<<dim3(DOUT / 128, MROWS / BM, 1), 256, 0, stream>>>(
      ar, w3b, out, zb, MROWS, DOUT, PDIM, PDIM, PDIM, DOUT, 0, 0, 0, 0, 0);
}